// Round 1
// baseline (2049.294 us; speedup 1.0000x reference)
//
#include <hip/hip_runtime.h>

typedef unsigned short u16;
typedef __attribute__((ext_vector_type(8))) short bf16x8;
typedef __attribute__((ext_vector_type(4))) float f32x4;

#define DD 2048
#define VV 10000
#define BB 32
#define TT 20

__device__ __forceinline__ u16 f2bf(float f) {
    unsigned u = __float_as_uint(f);
    u += 0x7fffu + ((u >> 16) & 1u);
    return (u16)(u >> 16);
}
__device__ __forceinline__ float bf2f(u16 h) {
    return __uint_as_float(((unsigned)h) << 16);
}

// ---------------------------------------------------------------------------
// One-time: cast the three per-step weight matrices to bf16.
// Wcat_a[8192][4096] = [Wih_a[:,0:2048] | Whh_a]      (x = [h_l ; h_a])
// Wcat_l[8192][4096] = [Wih_l[:,0:2048] | Whh_l]      (x = [h_a ; h_l])
// Wfc_b [10000][2048]
// ---------------------------------------------------------------------------
__global__ __launch_bounds__(256) void cast_weights(
    const float* __restrict__ Wih_a, const float* __restrict__ Whh_a,
    const float* __restrict__ Wih_l, const float* __restrict__ Whh_l,
    const float* __restrict__ Wfc,
    u16* __restrict__ Wcat_a, u16* __restrict__ Wcat_l, u16* __restrict__ Wfc_b)
{
    const long long S1 = 8192LL * 4096;
    const long long S3 = 20480000LL; // 10000*2048
    long long g = (long long)blockIdx.x * 256 + threadIdx.x;
    long long e = g * 4;
    const float* src;
    u16* dst;
    if (e < S1) {
        int n = (int)(e >> 12), k = (int)(e & 4095);
        src = (k < 2048) ? (Wih_a + (size_t)n * 6144 + k)
                         : (Whh_a + (size_t)n * 2048 + (k - 2048));
        dst = Wcat_a + e;
    } else if (e < 2 * S1) {
        long long e2 = e - S1;
        int n = (int)(e2 >> 12), k = (int)(e2 & 4095);
        src = (k < 2048) ? (Wih_l + (size_t)n * 4096 + k)
                         : (Whh_l + (size_t)n * 2048 + (k - 2048));
        dst = Wcat_l + e2;
    } else {
        long long e3 = e - 2 * S1;
        if (e3 >= S3) return;
        src = Wfc + e3;
        dst = Wfc_b + e3;
    }
    float4 v = *(const float4*)src;
    ushort4 o;
    o.x = f2bf(v.x); o.y = f2bf(v.y); o.z = f2bf(v.z); o.w = f2bf(v.w);
    *(ushort4*)dst = o;
}

// ---------------------------------------------------------------------------
// One-time: v_bar (mean over X), v_hat (sum over X -- attention weights are
// all-ones because softmax is over a singleton axis), zero the LSTM states.
// ---------------------------------------------------------------------------
__global__ __launch_bounds__(256) void prep(
    const float* __restrict__ features,
    u16* __restrict__ vbar, u16* __restrict__ vhat,
    float* __restrict__ c_a, float* __restrict__ c_l,
    u16* __restrict__ Ha0, u16* __restrict__ Hl0)
{
    int i = blockIdx.x * 256 + threadIdx.x;           // 32*2048
    int b = i >> 11, d = i & 2047;
    const float* f = features + (size_t)b * 36 * 2048 + d;
    float s = 0.f;
#pragma unroll
    for (int x = 0; x < 36; ++x) s += f[(size_t)x * 2048];
    vhat[i] = f2bf(s);
    vbar[i] = f2bf(s * (1.f / 36.f));
    c_a[i] = 0.f; c_l[i] = 0.f;
    Ha0[i] = 0;  Hl0[i] = 0;
}

// embedding gather -> bf16, rows m = t*32 + b
__global__ __launch_bounds__(256) void embed_k(
    const float* __restrict__ emb, const int* __restrict__ caption,
    u16* __restrict__ embs)
{
    int i = blockIdx.x * 256 + threadIdx.x;           // 640*2048
    int m = i >> 11, d = i & 2047;
    int t = m >> 5, b = m & 31;
    int tok = caption[b * TT + t];
    embs[i] = f2bf(emb[(size_t)tok * 2048 + d]);
}

// ---------------------------------------------------------------------------
// Precompute GEMM: out[m][n] = sum_k A[m][k]*W[n][kofs+k] (+bias0[n]+bias1[n])
// (+addend[m&31][n]).  A bf16 [M,2048]; W fp32 (cast inline).  N = 8192.
// block = 256 thr (4 waves x 16 n-cols); m-chunk = MT*16 rows per block.y
// ---------------------------------------------------------------------------
template <int MT>
__global__ __launch_bounds__(256) void pre_gemm(
    const u16* __restrict__ A, const float* __restrict__ W,
    int ldw, int kofs,
    const float* __restrict__ bias0, const float* __restrict__ bias1,
    const float* __restrict__ addend, float* __restrict__ out)
{
    const int lane = threadIdx.x & 63;
    const int wv = threadIdx.x >> 6;
    const int lr = lane & 15, lq = lane >> 4;
    const int n0 = blockIdx.x * 64 + wv * 16;
    const int m0 = blockIdx.y * (MT * 16);

    f32x4 acc[MT];
#pragma unroll
    for (int i = 0; i < MT; ++i) acc[i] = (f32x4){0.f, 0.f, 0.f, 0.f};

    const float* wrow = W + (size_t)(n0 + lr) * ldw + kofs + lq * 8;
    const u16* arow = A + (size_t)(m0 + lr) * 2048 + lq * 8;

    for (int k = 0; k < 2048; k += 32) {
        float4 wlo = *(const float4*)(wrow + k);
        float4 whi = *(const float4*)(wrow + k + 4);
        bf16x8 bf;
        bf[0] = (short)f2bf(wlo.x); bf[1] = (short)f2bf(wlo.y);
        bf[2] = (short)f2bf(wlo.z); bf[3] = (short)f2bf(wlo.w);
        bf[4] = (short)f2bf(whi.x); bf[5] = (short)f2bf(whi.y);
        bf[6] = (short)f2bf(whi.z); bf[7] = (short)f2bf(whi.w);
#pragma unroll
        for (int mt = 0; mt < MT; ++mt) {
            bf16x8 af = *(const bf16x8*)(arow + (size_t)mt * 16 * 2048 + k);
            acc[mt] = __builtin_amdgcn_mfma_f32_16x16x32_bf16(af, bf, acc[mt], 0, 0, 0);
        }
    }
    const int n = n0 + lr;
    float badd = 0.f;
    if (bias0) badd += bias0[n];
    if (bias1) badd += bias1[n];
#pragma unroll
    for (int mt = 0; mt < MT; ++mt) {
#pragma unroll
        for (int r = 0; r < 4; ++r) {
            int m = m0 + mt * 16 + lq * 4 + r;
            float v = acc[mt][r] + badd;
            if (addend) v += addend[(size_t)(m & 31) * 8192 + n];
            out[(size_t)m * 8192 + n] = v;
        }
    }
}

// ---------------------------------------------------------------------------
// Sequential step kernel: z[b][n] for n in {g*2048+d0+j}, fused LSTM gates.
// A = [A0 | A1] along K (each [32,2048] bf16).  W = [8192,4096] bf16 row-major.
// grid 128 blocks (16 d-cols each), 512 threads = 8 waves splitting K.
// ---------------------------------------------------------------------------
__global__ __launch_bounds__(512) void step_kernel(
    const u16* __restrict__ A0, const u16* __restrict__ A1,
    const u16* __restrict__ W, const float* __restrict__ zconst,
    float* __restrict__ c, u16* __restrict__ hout)
{
    __shared__ float zred[4][32][64];   // 32 KB
    const int lane = threadIdx.x & 63;
    const int w = threadIdx.x >> 6;
    const int lr = lane & 15, lq = lane >> 4;
    const int d0 = blockIdx.x * 16;

    const u16* Aptr = (w < 4) ? A0 : A1;
    const int kA = (w & 3) * 512 + lq * 8;   // col in A0/A1 (2048 wide)
    const int kW = w * 512 + lq * 8;         // col in Wcat   (4096 wide)

    f32x4 acc[2][4];
#pragma unroll
    for (int m = 0; m < 2; ++m)
#pragma unroll
        for (int g = 0; g < 4; ++g) acc[m][g] = (f32x4){0.f, 0.f, 0.f, 0.f};

    const u16* a_row0 = Aptr + (size_t)lr * 2048 + kA;
    const u16* a_row1 = Aptr + (size_t)(16 + lr) * 2048 + kA;
    const u16* b_row[4];
#pragma unroll
    for (int g = 0; g < 4; ++g)
        b_row[g] = W + (size_t)(g * 2048 + d0 + lr) * 4096 + kW;

    for (int kk = 0; kk < 512; kk += 32) {
        bf16x8 a0 = *(const bf16x8*)(a_row0 + kk);
        bf16x8 a1 = *(const bf16x8*)(a_row1 + kk);
#pragma unroll
        for (int g = 0; g < 4; ++g) {
            bf16x8 bf = *(const bf16x8*)(b_row[g] + kk);
            acc[0][g] = __builtin_amdgcn_mfma_f32_16x16x32_bf16(a0, bf, acc[0][g], 0, 0, 0);
            acc[1][g] = __builtin_amdgcn_mfma_f32_16x16x32_bf16(a1, bf, acc[1][g], 0, 0, 0);
        }
    }

    // two-stage reduction in 32 KB LDS: waves 4-7 write, waves 0-3 add.
    if (w >= 4) {
#pragma unroll
        for (int m = 0; m < 2; ++m)
#pragma unroll
            for (int g = 0; g < 4; ++g)
#pragma unroll
                for (int r = 0; r < 4; ++r)
                    zred[w - 4][m * 16 + lq * 4 + r][g * 16 + lr] = acc[m][g][r];
    }
    __syncthreads();
    if (w < 4) {
#pragma unroll
        for (int m = 0; m < 2; ++m)
#pragma unroll
            for (int g = 0; g < 4; ++g)
#pragma unroll
                for (int r = 0; r < 4; ++r)
                    zred[w][m * 16 + lq * 4 + r][g * 16 + lr] += acc[m][g][r];
    }
    __syncthreads();

    // gates: 512 threads <-> (b, j)
    const int b = threadIdx.x >> 4;
    const int j = threadIdx.x & 15;
    const int d = d0 + j;
    float z[4];
#pragma unroll
    for (int g = 0; g < 4; ++g) {
        float s = zconst[(size_t)b * 8192 + g * 2048 + d];
#pragma unroll
        for (int wv = 0; wv < 4; ++wv) s += zred[wv][b][g * 16 + j];
        z[g] = s;
    }
    float ig = 1.f / (1.f + __expf(-z[0]));
    float fg = 1.f / (1.f + __expf(-z[1]));
    float gg = tanhf(z[2]);
    float og = 1.f / (1.f + __expf(-z[3]));
    float cn = fg * c[(size_t)b * 2048 + d] + ig * gg;
    c[(size_t)b * 2048 + d] = cn;
    hout[(size_t)b * 2048 + d] = f2bf(og * tanhf(cn));
}

// ---------------------------------------------------------------------------
// Logits GEMM: out[b][t][n] = sum_k Hl[t+1][b][k]*Wfc_b[n][k] + bfc[n]
// A rows m = t*32+b.  N = 10000 (625 16-tiles).
// ---------------------------------------------------------------------------
template <int MT>
__global__ __launch_bounds__(256) void logits_gemm(
    const u16* __restrict__ A, const u16* __restrict__ Wb,
    const float* __restrict__ bias, float* __restrict__ out)
{
    const int lane = threadIdx.x & 63;
    const int wv = threadIdx.x >> 6;
    const int lr = lane & 15, lq = lane >> 4;
    const int n0 = blockIdx.x * 64 + wv * 16;
    if (n0 >= VV) return;
    const int m0 = blockIdx.y * (MT * 16);

    f32x4 acc[MT];
#pragma unroll
    for (int i = 0; i < MT; ++i) acc[i] = (f32x4){0.f, 0.f, 0.f, 0.f};

    const u16* wrow = Wb + (size_t)(n0 + lr) * 2048 + lq * 8;
    const u16* arow = A + (size_t)(m0 + lr) * 2048 + lq * 8;

    for (int k = 0; k < 2048; k += 32) {
        bf16x8 bf = *(const bf16x8*)(wrow + k);
#pragma unroll
        for (int mt = 0; mt < MT; ++mt) {
            bf16x8 af = *(const bf16x8*)(arow + (size_t)mt * 16 * 2048 + k);
            acc[mt] = __builtin_amdgcn_mfma_f32_16x16x32_bf16(af, bf, acc[mt], 0, 0, 0);
        }
    }
    const int n = n0 + lr;
    const float bv = bias[n];
#pragma unroll
    for (int mt = 0; mt < MT; ++mt) {
#pragma unroll
        for (int r = 0; r < 4; ++r) {
            int m = m0 + mt * 16 + lq * 4 + r;
            int t = m >> 5, b = m & 31;
            out[(size_t)b * (TT * VV) + (size_t)t * VV + n] = acc[mt][r] + bv;
        }
    }
}

// in-place log-softmax over rows of 10000
__global__ __launch_bounds__(256) void logsoftmax(float* __restrict__ out)
{
    float* p = out + (size_t)blockIdx.x * VV;
    const int tid = threadIdx.x, lane = tid & 63, wv = tid >> 6;
    __shared__ float red[4], red2[4];
    float mx = -1e30f;
    for (int i = tid; i < VV; i += 256) mx = fmaxf(mx, p[i]);
    for (int o = 32; o > 0; o >>= 1) mx = fmaxf(mx, __shfl_down(mx, o, 64));
    if (lane == 0) red[wv] = mx;
    __syncthreads();
    mx = fmaxf(fmaxf(red[0], red[1]), fmaxf(red[2], red[3]));
    float sum = 0.f;
    for (int i = tid; i < VV; i += 256) sum += __expf(p[i] - mx);
    for (int o = 32; o > 0; o >>= 1) sum += __shfl_down(sum, o, 64);
    if (lane == 0) red2[wv] = sum;
    __syncthreads();
    sum = red2[0] + red2[1] + red2[2] + red2[3];
    const float lse = mx + __logf(sum);
    for (int i = tid; i < VV; i += 256) p[i] = p[i] - lse;
}

// ---------------------------------------------------------------------------
extern "C" void kernel_launch(void* const* d_in, const int* in_sizes, int n_in,
                              void* d_out, int out_size, void* d_ws, size_t ws_size,
                              hipStream_t stream)
{
    const float* features = (const float*)d_in[0];
    const int*   caption  = (const int*)d_in[1];
    const float* emb      = (const float*)d_in[2];
    const float* Wih_a    = (const float*)d_in[3];
    const float* Whh_a    = (const float*)d_in[4];
    const float* bih_a    = (const float*)d_in[5];
    const float* bhh_a    = (const float*)d_in[6];
    const float* Wih_l    = (const float*)d_in[7];
    const float* Whh_l    = (const float*)d_in[8];
    const float* bih_l    = (const float*)d_in[9];
    const float* bhh_l    = (const float*)d_in[10];
    // d_in[11..16] = Wv,bv,Wh,bh,Wa,ba : DEAD (softmax over singleton axis)
    const float* Wfc      = (const float*)d_in[17];
    const float* bfc      = (const float*)d_in[18];
    float* out = (float*)d_out;

    char* ws = (char*)d_ws;
    size_t off = 0;
    auto alloc = [&](size_t bytes) { void* p = ws + off; off += (bytes + 255) & ~(size_t)255; return p; };
    u16* Wcat_a  = (u16*)alloc(8192ull * 4096 * 2);       // 67.1 MB
    u16* Wcat_l  = (u16*)alloc(8192ull * 4096 * 2);       // 67.1 MB
    u16* Wfc_b   = (u16*)alloc(10000ull * 2048 * 2);      // 41.0 MB
    float* z_const = (float*)alloc(20ull * 32 * 8192 * 4);// 21.0 MB
    float* const_a = (float*)alloc(32ull * 8192 * 4);
    float* const_l = (float*)alloc(32ull * 8192 * 4);
    u16* embs    = (u16*)alloc(640ull * 2048 * 2);
    u16* vbar    = (u16*)alloc(32ull * 2048 * 2);
    u16* vhat    = (u16*)alloc(32ull * 2048 * 2);
    u16* Ha      = (u16*)alloc(2ull * 32 * 2048 * 2);
    u16* Hl      = (u16*)alloc(21ull * 32 * 2048 * 2);
    float* c_a   = (float*)alloc(32ull * 2048 * 4);
    float* c_l   = (float*)alloc(32ull * 2048 * 4);
    (void)ws_size; (void)in_sizes; (void)n_in; (void)out_size;

    // one-time precompute
    cast_weights<<<dim3(85536), dim3(256), 0, stream>>>(
        Wih_a, Whh_a, Wih_l, Whh_l, Wfc, Wcat_a, Wcat_l, Wfc_b);
    prep<<<dim3(256), dim3(256), 0, stream>>>(features, vbar, vhat, c_a, c_l, Ha, Hl);
    embed_k<<<dim3(5120), dim3(256), 0, stream>>>(emb, caption, embs);
    // const_a[b][n] = vbar @ Wih_a[:,2048:4096]^T + bih_a + bhh_a
    pre_gemm<2><<<dim3(128, 1), dim3(256), 0, stream>>>(
        vbar, Wih_a, 6144, 2048, bih_a, bhh_a, nullptr, const_a);
    // const_l[b][n] = vhat @ Wih_l[:,2048:4096]^T + bih_l + bhh_l
    pre_gemm<2><<<dim3(128, 1), dim3(256), 0, stream>>>(
        vhat, Wih_l, 4096, 2048, bih_l, bhh_l, nullptr, const_l);
    // z_const[t*32+b][n] = embs @ Wih_a[:,4096:6144]^T + const_a[b]
    pre_gemm<10><<<dim3(128, 4), dim3(256), 0, stream>>>(
        embs, Wih_a, 6144, 4096, nullptr, nullptr, const_a, z_const);

    // sequential 20-step dual-LSTM loop (2 fused GEMM+gate kernels per step)
    for (int t = 0; t < 20; ++t) {
        u16* hl_prev = Hl + (size_t)t * 65536;
        u16* ha_prev = Ha + (size_t)(t & 1) * 65536;
        u16* ha_new  = Ha + (size_t)((t + 1) & 1) * 65536;
        u16* hl_new  = Hl + (size_t)(t + 1) * 65536;
        // attention LSTM: x=[h_l ; h_a] vs [Wih_a[:,0:2048] | Whh_a]
        step_kernel<<<dim3(128), dim3(512), 0, stream>>>(
            hl_prev, ha_prev, Wcat_a, z_const + (size_t)t * 262144, c_a, ha_new);
        // language LSTM: x=[h_a ; h_l] vs [Wih_l[:,0:2048] | Whh_l]
        step_kernel<<<dim3(128), dim3(512), 0, stream>>>(
            ha_new, hl_prev, Wcat_l, const_l, c_l, hl_new);
    }

    // batched logits + log-softmax
    logits_gemm<10><<<dim3(157, 4), dim3(256), 0, stream>>>(Hl + 65536, Wfc_b, bfc, out);
    logsoftmax<<<dim3(640), dim3(256), 0, stream>>>(out);
}